// Round 4
// baseline (729.976 us; speedup 1.0000x reference)
//
#include <hip/hip_runtime.h>

// Sparse MoE: T=4096 tokens, d=1024, E=8 experts, top-2, ffn=4096.
// route -> compact per-expert row lists -> bf16 MFMA grouped GEMM1 (gelu) ->
// GEMM2 split-K=4 (deterministic bf16 partials) -> combine.
// R2: GEMMs rewritten to the 256^2 8-phase schedule (T2+T3+T4+T5, m194-m201
// template; grouped-K=1024 evidence m248: 848 vs 655 TF for 2-phase).
// 512 thr / 8 waves (2Mx4N), BK=64, 2 LDS K-tile buffers (128 KiB), staging
// spread 2-3 loads/phase honoring region last-read phases, counted
// s_waitcnt vmcnt(6) at phases 4/8 only (never 0 in steady state),
// s_setprio(1) around each 16-MFMA cluster. Proven R0 XOR chunk swizzle
// (0 bank conflicts measured) reused for LDS addressing.
// R3: resubmit unchanged (round-3 bench was a broker-level container failure,
// same as round 0's flake on the known-good kernel; schedule re-audited:
// waitcnt FIFO arithmetic, region lifetimes, bounds, barrier uniformity OK).

#define TOKENS 4096
#define DMODEL 1024
#define NEXP   8
#define DFF    4096
#define NROWS  (2*TOKENS)
#define SPLITK 4

typedef __bf16 bf16_t;
typedef __bf16 bf16x8 __attribute__((ext_vector_type(8)));
typedef __bf16 bf16x4 __attribute__((ext_vector_type(4)));
typedef float  f32x4  __attribute__((ext_vector_type(4)));

__device__ __forceinline__ void gl_lds16(const void* g, void* l) {
    __builtin_amdgcn_global_load_lds(
        (const __attribute__((address_space(1))) void*)g,
        (__attribute__((address_space(3))) void*)l, 16, 0, 0);
}

// ---------------- router ----------------
__global__ __launch_bounds__(64) void router_k(
    const float* __restrict__ x, const float* __restrict__ rw,
    const float* __restrict__ rb, int* __restrict__ cnt,
    int* __restrict__ tok_e, int* __restrict__ tok_pos,
    float* __restrict__ tok_w, float* __restrict__ probs,
    bf16_t* __restrict__ xb)
{
    int t = blockIdx.x;
    int lane = threadIdx.x;
    const float* xr = x + (size_t)t * DMODEL;
    bf16_t* xbr = xb + (size_t)t * DMODEL;
    float s[NEXP];
#pragma unroll
    for (int e = 0; e < NEXP; e++) s[e] = 0.f;
    for (int i = lane; i < DMODEL; i += 64) {
        float xv = xr[i];
        xbr[i] = (bf16_t)xv;
        const float* wr = rw + (size_t)i * NEXP;
#pragma unroll
        for (int e = 0; e < NEXP; e++) s[e] += xv * wr[e];
    }
#pragma unroll
    for (int e = 0; e < NEXP; e++) {
#pragma unroll
        for (int o = 32; o > 0; o >>= 1) s[e] += __shfl_down(s[e], o, 64);
    }
    if (lane == 0) {
        float mx = -1e30f;
#pragma unroll
        for (int e = 0; e < NEXP; e++) { s[e] += rb[e]; mx = fmaxf(mx, s[e]); }
        float den = 0.f;
#pragma unroll
        for (int e = 0; e < NEXP; e++) { s[e] = expf(s[e] - mx); den += s[e]; }
        float inv = 1.f / den;
#pragma unroll
        for (int e = 0; e < NEXP; e++) { s[e] *= inv; probs[t * NEXP + e] = s[e]; }
        int e0 = 0;
#pragma unroll
        for (int e = 1; e < NEXP; e++) if (s[e] > s[e0]) e0 = e;
        int e1 = (e0 == 0) ? 1 : 0;
#pragma unroll
        for (int e = 0; e < NEXP; e++) if (e != e0 && s[e] > s[e1]) e1 = e;
        float sw = s[e0] + s[e1];
        int p0 = atomicAdd(&cnt[e0], 1);
        int p1 = atomicAdd(&cnt[e1], 1);
        tok_e[2 * t] = e0;       tok_e[2 * t + 1] = e1;
        tok_pos[2 * t] = p0;     tok_pos[2 * t + 1] = p1;
        tok_w[2 * t] = s[e0] / sw; tok_w[2 * t + 1] = s[e1] / sw;
    }
}

__global__ void offsets_k(const int* __restrict__ cnt, int* __restrict__ off)
{
    if (threadIdx.x == 0) {
        int a = 0;
        for (int e = 0; e < NEXP; e++) { off[e] = a; a += cnt[e]; }
        off[NEXP] = a;
    }
}

__global__ void scatter_k(const int* __restrict__ tok_e, const int* __restrict__ tok_pos,
                          const float* __restrict__ tok_w, const int* __restrict__ off,
                          int* __restrict__ rows_tok, float* __restrict__ roww,
                          int* __restrict__ g_of)
{
    int i = blockIdx.x * blockDim.x + threadIdx.x;
    if (i < 2 * TOKENS) {
        int e = tok_e[i];
        int g = off[e] + tok_pos[i];
        rows_tok[g] = i >> 1;
        roww[g] = tok_w[i];
        g_of[i] = g;
    }
}

// ---------------- transpose+convert: [E][K][N] f32 -> [E][N][K] bf16 ------------
#define TP 65
__global__ __launch_bounds__(256) void transconv_k(const float* __restrict__ in,
                                                   bf16_t* __restrict__ o, int K, int N)
{
    __shared__ float t[64 * TP];
    int e = blockIdx.z;
    int n0 = blockIdx.x * 64, k0 = blockIdx.y * 64;
    int tid = threadIdx.x;
    int c4 = tid & 15, r = tid >> 4;
    const float* src = in + ((size_t)e * K + k0) * N + n0;
#pragma unroll
    for (int p = 0; p < 4; p++) {
        int k = r + p * 16;
        float4 v = *(const float4*)(src + (size_t)k * N + c4 * 4);
        float* d = &t[k * TP + c4 * 4];
        d[0] = v.x; d[1] = v.y; d[2] = v.z; d[3] = v.w;
    }
    __syncthreads();
    int k8 = tid & 7, n = tid >> 3;
    bf16_t* dst = o + ((size_t)e * N + n0) * K + k0;
#pragma unroll
    for (int p = 0; p < 2; p++) {
        int nn = n + p * 32;
        bf16x8 w;
#pragma unroll
        for (int j = 0; j < 8; j++) w[j] = (bf16_t)t[(k8 * 8 + j) * TP + nn];
        *(bf16x8*)(dst + (size_t)nn * K + k8 * 8) = w;
    }
}

// ---------------- 8-phase 256x256 grouped GEMM (MODE 0: gemm1, MODE 1: gemm2) ----
// K=1024 (16 tiles of BK=64), 8 waves, per-wave 128x64 output, acc[8][4].
// LDS: 2 K-tile buffers (A 32KB + B 32KB each) = 128 KiB.
// Staging schedule per iteration i (computes tiles E=2i bufA p1-4, O=2i+1 bufB
// p5-8; stages E'=2i+2 -> bufA, O'=2i+3 -> bufB), region-safe vs last reads
// (A rows 0-63 & 128-191 dead after phase 2; 64-127 & 192-255 after phase 4;
//  B dead after phase 1):
//   p1: A1,A3 of tile 2i+1 -> bufB     p5: A1,A3 of E' -> bufA
//   p2: B0,B1 of E' -> bufA            p6: B0,B1 of O' -> bufB
//   p3: B2,B3,A0 of E' -> bufA         p7: B2,B3,A0 of O' -> bufB
//   p4: A2 of E' -> bufA  [vmcnt(6)]   p8: A2 of O' -> bufB  [vmcnt(6)]
// Wait arithmetic (FIFO): 14 outstanding at each W6 -> completes oldest 8 =
// exactly the tile consumed in the next 4 phases.

#define STG_A(BUF, J, KK) gl_lds16(arow[J] + (KK) * 64 + sc8, &(BUF)[(J) * 4096 + wave * 512])
#define STG_B(BUF, J, KK) gl_lds16(brow[J] + (KK) * 64 + sc8, &(BUF)[(J) * 4096 + wave * 512])
#define W6 asm volatile("s_waitcnt vmcnt(6)" ::: "memory")
#define W0 asm volatile("s_waitcnt vmcnt(0)" ::: "memory")
#define NOSTG (void)0
#define NOWAIT (void)0

#define PH(LA, LB, P, STAGE, WAIT)                                              \
  do {                                                                          \
    bf16x8 af_[2][2];                                                           \
    _Pragma("unroll")                                                           \
    for (int dm_ = 0; dm_ < 2; dm_++) {                                         \
        int r_ = wrow * 128 + (2 * (P) + dm_) * 16 + (lane & 15);               \
        _Pragma("unroll")                                                       \
        for (int ks_ = 0; ks_ < 2; ks_++) {                                     \
            int ch_ = (ks_ * 4 + (lane >> 4)) ^ (r_ & 7);                       \
            af_[dm_][ks_] = *(const bf16x8*)&(LA)[r_ * 64 + ch_ * 8];           \
        }                                                                       \
    }                                                                           \
    if ((P) == 0) {                                                             \
        _Pragma("unroll")                                                       \
        for (int nt_ = 0; nt_ < 4; nt_++) {                                     \
            int c_ = wcol * 64 + nt_ * 16 + (lane & 15);                        \
            _Pragma("unroll")                                                   \
            for (int ks_ = 0; ks_ < 2; ks_++) {                                 \
                int ch_ = (ks_ * 4 + (lane >> 4)) ^ (c_ & 7);                   \
                bfr[nt_][ks_] = *(const bf16x8*)&(LB)[c_ * 64 + ch_ * 8];       \
            }                                                                   \
        }                                                                       \
    }                                                                           \
    STAGE;                                                                      \
    __builtin_amdgcn_s_barrier();                                               \
    asm volatile("s_waitcnt lgkmcnt(0)" ::: "memory");                          \
    __builtin_amdgcn_s_setprio(1);                                              \
    _Pragma("unroll")                                                           \
    for (int dm_ = 0; dm_ < 2; dm_++)                                           \
        _Pragma("unroll")                                                       \
        for (int nt_ = 0; nt_ < 4; nt_++)                                       \
            _Pragma("unroll")                                                   \
            for (int ks_ = 0; ks_ < 2; ks_++)                                   \
                acc[2 * (P) + dm_][nt_] = __builtin_amdgcn_mfma_f32_16x16x32_bf16( \
                    af_[dm_][ks_], bfr[nt_][ks_], acc[2 * (P) + dm_][nt_], 0, 0, 0); \
    __builtin_amdgcn_s_setprio(0);                                              \
    WAIT;                                                                       \
    __builtin_amdgcn_s_barrier();                                               \
  } while (0)

template <int MODE>
__global__ __launch_bounds__(512, 2) void gemm8p_k(
    const bf16_t* __restrict__ A, const bf16_t* __restrict__ Bt,
    const float* __restrict__ bias,
    const int* __restrict__ cnt, const int* __restrict__ off,
    const int* __restrict__ rows_tok, bf16_t* __restrict__ outb)
{
    int bid = blockIdx.x;
    int e = bid & 7;                       // XCD pin
    int rest = bid >> 3;
    int yt = rest & 15;
    int xt, kt;
    if (MODE == 0) { xt = rest >> 4; kt = 0; }
    else           { xt = (rest >> 4) & 3; kt = rest >> 6; }
    int M = cnt[e];
    int m0 = yt * 256;
    if (m0 >= M) return;
    int n0 = xt * 256;
    int base = off[e];
    const int k0 = (MODE == 0) ? 0 : kt * (DFF / SPLITK);

    __shared__ __align__(16) bf16_t lds[4 * 16384];   // 128 KiB
    bf16_t* lA0 = lds;
    bf16_t* lB0 = lds + 16384;
    bf16_t* lA1 = lds + 32768;
    bf16_t* lB1 = lds + 49152;

    int tid = threadIdx.x;
    int wave = tid >> 6;
    int lane = tid & 63;
    int wrow = wave >> 2;                  // 0..1
    int wcol = wave & 3;                   // 0..3
    int srow = tid >> 3;                   // 0..63 staging row within 64-group
    int sc8 = ((tid & 7) ^ (srow & 7)) * 8;  // pre-swizzled global chunk offset

    const bf16_t* arow[4];
    const bf16_t* brow[4];
#pragma unroll
    for (int j = 0; j < 4; j++) {
        int gr = m0 + j * 64 + srow; if (gr > M - 1) gr = M - 1;
        if (MODE == 0) {
            int tok = rows_tok[base + gr];
            arow[j] = A + (size_t)tok * DMODEL;
            brow[j] = Bt + ((size_t)e * DFF + n0 + j * 64 + srow) * DMODEL;
        } else {
            arow[j] = A + (size_t)(base + gr) * DFF + k0;
            brow[j] = Bt + ((size_t)e * DMODEL + n0 + j * 64 + srow) * DFF + k0;
        }
    }

    f32x4 acc[8][4];
    f32x4 zero = { 0.f, 0.f, 0.f, 0.f };
#pragma unroll
    for (int i = 0; i < 8; i++)
#pragma unroll
        for (int j = 0; j < 4; j++) acc[i][j] = zero;
    bf16x8 bfr[4][2];

    // prologue: tile0 fully; tile1 all but A1,A3 (those staged at p1 of iter 0)
    STG_B(lB0, 0, 0); STG_B(lB0, 1, 0); STG_B(lB0, 2, 0); STG_B(lB0, 3, 0);
    STG_A(lA0, 0, 0); STG_A(lA0, 1, 0); STG_A(lA0, 2, 0); STG_A(lA0, 3, 0);
    STG_B(lB1, 0, 1); STG_B(lB1, 1, 1); STG_B(lB1, 2, 1); STG_B(lB1, 3, 1);
    STG_A(lA1, 0, 1); STG_A(lA1, 2, 1);
    W6;                                   // tile0 (oldest 8) complete
    __builtin_amdgcn_s_barrier();

#pragma unroll 1
    for (int i = 0; i < 7; i++) {
        int tO1 = 2 * i + 1, tE2 = 2 * i + 2, tO3 = 2 * i + 3;
        PH(lA0, lB0, 0, { STG_A(lA1, 1, tO1); STG_A(lA1, 3, tO1); }, NOWAIT);
        PH(lA0, lB0, 1, { STG_B(lB0, 0, tE2); STG_B(lB0, 1, tE2); }, NOWAIT);
        PH(lA0, lB0, 2, { STG_B(lB0, 2, tE2); STG_B(lB0, 3, tE2); STG_A(lA0, 0, tE2); }, NOWAIT);
        PH(lA0, lB0, 3, { STG_A(lA0, 2, tE2); }, W6);
        PH(lA1, lB1, 0, { STG_A(lA0, 1, tE2); STG_A(lA0, 3, tE2); }, NOWAIT);
        PH(lA1, lB1, 1, { STG_B(lB1, 0, tO3); STG_B(lB1, 1, tO3); }, NOWAIT);
        PH(lA1, lB1, 2, { STG_B(lB1, 2, tO3); STG_B(lB1, 3, tO3); STG_A(lA1, 0, tO3); }, NOWAIT);
        PH(lA1, lB1, 3, { STG_A(lA1, 2, tO3); }, W6);
    }
    // peeled last iteration: tiles 14 (bufA), 15 (bufB); drain with vmcnt(0)
    PH(lA0, lB0, 0, { STG_A(lA1, 1, 15); STG_A(lA1, 3, 15); }, NOWAIT);
    PH(lA0, lB0, 1, NOSTG, NOWAIT);
    PH(lA0, lB0, 2, NOSTG, NOWAIT);
    PH(lA0, lB0, 3, NOSTG, W0);
    PH(lA1, lB1, 0, NOSTG, NOWAIT);
    PH(lA1, lB1, 1, NOSTG, NOWAIT);
    PH(lA1, lB1, 2, NOSTG, NOWAIT);
    PH(lA1, lB1, 3, NOSTG, NOWAIT);

    // ---------------- epilogue ----------------
    // C/D map: col = lane&15, row = (lane>>4)*4 + reg  [m89/m91]
    if (MODE == 0) {
        float bv[4];
#pragma unroll
        for (int nt = 0; nt < 4; nt++)
            bv[nt] = bias[(size_t)e * DFF + n0 + wcol * 64 + nt * 16 + (lane & 15)];
#pragma unroll
        for (int mt = 0; mt < 8; mt++) {
#pragma unroll
            for (int q = 0; q < 4; q++) {
                int r = wrow * 128 + mt * 16 + (lane >> 4) * 4 + q;
                int gm = m0 + r;
                if (gm < M) {
                    size_t hrow = (size_t)(base + gm) * DFF;
#pragma unroll
                    for (int nt = 0; nt < 4; nt++) {
                        float v = acc[mt][nt][q] + bv[nt];
                        v = 0.5f * v * (1.f + erff(v * 0.70710678118654752f));
                        int c = n0 + wcol * 64 + nt * 16 + (lane & 15);
                        outb[hrow + c] = (bf16_t)v;
                    }
                }
            }
        }
    } else {
#pragma unroll
        for (int mt = 0; mt < 8; mt++) {
#pragma unroll
            for (int q = 0; q < 4; q++) {
                int r = wrow * 128 + mt * 16 + (lane >> 4) * 4 + q;
                int gm = m0 + r;
                if (gm < M) {
                    size_t yrow = ((size_t)kt * NROWS + base + gm) * DMODEL;
#pragma unroll
                    for (int nt = 0; nt < 4; nt++) {
                        int c = n0 + wcol * 64 + nt * 16 + (lane & 15);
                        outb[yrow + c] = (bf16_t)acc[mt][nt][q];
                    }
                }
            }
        }
    }
}

// ---------------- combine ----------------
__global__ __launch_bounds__(256) void combine_k(
    const bf16_t* __restrict__ ybuf, const int* __restrict__ g_of,
    const int* __restrict__ tok_e, const float* __restrict__ tok_w,
    const float* __restrict__ b2, float* __restrict__ out)
{
    int t = blockIdx.x;
    int c = threadIdx.x * 4;
    int g0 = g_of[2 * t], g1 = g_of[2 * t + 1];
    int e0 = tok_e[2 * t], e1 = tok_e[2 * t + 1];
    float w0 = tok_w[2 * t], w1 = tok_w[2 * t + 1];
    float a0[4] = {0.f, 0.f, 0.f, 0.f}, a1[4] = {0.f, 0.f, 0.f, 0.f};
#pragma unroll
    for (int kt = 0; kt < SPLITK; kt++) {
        bf16x4 y0 = *(const bf16x4*)&ybuf[((size_t)kt * NROWS + g0) * DMODEL + c];
        bf16x4 y1 = *(const bf16x4*)&ybuf[((size_t)kt * NROWS + g1) * DMODEL + c];
#pragma unroll
        for (int j = 0; j < 4; j++) { a0[j] += (float)y0[j]; a1[j] += (float)y1[j]; }
    }
    float4 bb0 = *(const float4*)&b2[(size_t)e0 * DMODEL + c];
    float4 bb1 = *(const float4*)&b2[(size_t)e1 * DMODEL + c];
    float4 r;
    r.x = w0 * (a0[0] + bb0.x) + w1 * (a1[0] + bb1.x);
    r.y = w0 * (a0[1] + bb0.y) + w1 * (a1[1] + bb1.y);
    r.z = w0 * (a0[2] + bb0.z) + w1 * (a1[2] + bb1.z);
    r.w = w0 * (a0[3] + bb0.w) + w1 * (a1[3] + bb1.w);
    *(float4*)&out[(size_t)t * DMODEL + c] = r;
}

// ---------------- aux loss ----------------
__global__ __launch_bounds__(256) void aux_k(const float* __restrict__ probs,
                                             float* __restrict__ out_aux)
{
    __shared__ float red[256];
    __shared__ float mexp[NEXP];
    float s[NEXP];
#pragma unroll
    for (int e = 0; e < NEXP; e++) s[e] = 0.f;
    for (int t = threadIdx.x; t < TOKENS; t += 256) {
#pragma unroll
        for (int e = 0; e < NEXP; e++) s[e] += probs[t * NEXP + e];
    }
    for (int e = 0; e < NEXP; e++) {
        red[threadIdx.x] = s[e];
        __syncthreads();
        for (int st = 128; st > 0; st >>= 1) {
            if (threadIdx.x < st) red[threadIdx.x] += red[threadIdx.x + st];
            __syncthreads();
        }
        if (threadIdx.x == 0) mexp[e] = red[0] / (float)TOKENS;
        __syncthreads();
    }
    if (threadIdx.x == 0) {
        float mean = 0.f;
        for (int e = 0; e < NEXP; e++) mean += mexp[e];
        mean /= (float)NEXP;
        float v = 0.f;
        for (int e = 0; e < NEXP; e++) { float d = mexp[e] - mean; v += d * d; }
        out_aux[0] = v / (float)(NEXP - 1);
    }
}

extern "C" void kernel_launch(void* const* d_in, const int* in_sizes, int n_in,
                              void* d_out, int out_size, void* d_ws, size_t ws_size,
                              hipStream_t stream)
{
    const float* x  = (const float*)d_in[0];
    const float* rw = (const float*)d_in[1];
    const float* rb = (const float*)d_in[2];
    const float* w1 = (const float*)d_in[3];
    const float* b1 = (const float*)d_in[4];
    const float* w2 = (const float*)d_in[5];
    const float* b2 = (const float*)d_in[6];
    float* out = (float*)d_out;

    char* p = (char*)d_ws;
    auto alloc = [&](size_t b) { char* q = p; p += (b + 255) & ~(size_t)255; return q; };
    int*    cnt      = (int*)   alloc(NEXP * sizeof(int));
    int*    off      = (int*)   alloc((NEXP + 1) * sizeof(int));
    int*    tok_e    = (int*)   alloc(2 * TOKENS * sizeof(int));
    int*    tok_pos  = (int*)   alloc(2 * TOKENS * sizeof(int));
    float*  tok_w    = (float*) alloc(2 * TOKENS * sizeof(float));
    int*    rows_tok = (int*)   alloc(NROWS * sizeof(int));
    float*  roww     = (float*) alloc(NROWS * sizeof(float));
    int*    g_of     = (int*)   alloc(2 * TOKENS * sizeof(int));
    float*  probs    = (float*) alloc((size_t)TOKENS * NEXP * sizeof(float));
    bf16_t* xb       = (bf16_t*)alloc((size_t)TOKENS * DMODEL * 2);
    bf16_t* w1t      = (bf16_t*)alloc((size_t)NEXP * DFF * DMODEL * 2);
    bf16_t* w2t      = (bf16_t*)alloc((size_t)NEXP * DMODEL * DFF * 2);
    bf16_t* hbuf     = (bf16_t*)alloc((size_t)NROWS * DFF * 2);
    // ybuf aliases w1t (dead after gemm1; gemm2 strictly after on same stream)
    bf16_t* ybuf     = w1t;

    hipMemsetAsync(cnt, 0, NEXP * sizeof(int), stream);

    router_k<<<TOKENS, 64, 0, stream>>>(x, rw, rb, cnt, tok_e, tok_pos, tok_w, probs, xb);
    offsets_k<<<1, 64, 0, stream>>>(cnt, off);
    scatter_k<<<(2 * TOKENS + 255) / 256, 256, 0, stream>>>(tok_e, tok_pos, tok_w, off,
                                                            rows_tok, roww, g_of);
    transconv_k<<<dim3(DFF / 64, DMODEL / 64, NEXP), 256, 0, stream>>>(w1, w1t, DMODEL, DFF);
    transconv_k<<<dim3(DMODEL / 64, DFF / 64, NEXP), 256, 0, stream>>>(w2, w2t, DFF, DMODEL);

    gemm8p_k<0><<<NEXP * 16 * 16, 512, 0, stream>>>(xb, w1t, b1, cnt, off, rows_tok, hbuf);
    gemm8p_k<1><<<NEXP * 16 * 4 * SPLITK, 512, 0, stream>>>(hbuf, w2t, nullptr, cnt, off,
                                                            nullptr, ybuf);
    combine_k<<<TOKENS, 256, 0, stream>>>(ybuf, g_of, tok_e, tok_w, b2, out);

    aux_k<<<1, 256, 0, stream>>>(probs, out + (size_t)TOKENS * DMODEL);
}

// Round 5
// 658.519 us; speedup vs baseline: 1.1085x; 1.1085x over previous
//
#include <hip/hip_runtime.h>

// Sparse MoE: T=4096 tokens, d=1024, E=8 experts, top-2, ffn=4096.
// route -> compact per-expert row lists (2T rows) -> bf16 MFMA grouped GEMM1
// (gelu) -> GEMM2 split-K=2 (deterministic bf16 partials, no atomics) ->
// combine (token-major weighted sum + bias). Expert e pinned to XCD e via
// bid&7. GEMMs: the R0-verified 2-barrier 128^2 gl_lds structure (516 TF).
// R4: reverted R1/R2 structural experiments (dbuf 64KB: occ 28->15%, 8-phase
// 128KB: 1 blk/CU, MfmaUtil 16% -- both lose the cross-block TLP that makes
// the 2-barrier template work). New: SPLITK 4->2 (halves partial traffic,
// keeps 4 blk/CU + ~L2-fit A half-slab), router 4 tok/block with float4.

#define TOKENS 4096
#define DMODEL 1024
#define NEXP   8
#define DFF    4096
#define NROWS  (2*TOKENS)
#define SPLITK 2

typedef __bf16 bf16_t;
typedef __bf16 bf16x8 __attribute__((ext_vector_type(8)));
typedef __bf16 bf16x4 __attribute__((ext_vector_type(4)));
typedef float  f32x4  __attribute__((ext_vector_type(4)));

__device__ __forceinline__ void gl_lds16(const void* g, void* l) {
    __builtin_amdgcn_global_load_lds(
        (const __attribute__((address_space(1))) void*)g,
        (__attribute__((address_space(3))) void*)l, 16, 0, 0);
}

// ---------------- router: 4 tokens/block (1 per wave), float4 loads ----------
__global__ __launch_bounds__(256) void router_k(
    const float* __restrict__ x, const float* __restrict__ rw,
    const float* __restrict__ rb, int* __restrict__ cnt,
    int* __restrict__ tok_e, int* __restrict__ tok_pos,
    float* __restrict__ tok_w, float* __restrict__ probs,
    bf16_t* __restrict__ xb)
{
    int w = threadIdx.x >> 6;
    int lane = threadIdx.x & 63;
    int t = blockIdx.x * 4 + w;
    const float* xr = x + (size_t)t * DMODEL;
    bf16_t* xbr = xb + (size_t)t * DMODEL;
    float s[NEXP];
#pragma unroll
    for (int e = 0; e < NEXP; e++) s[e] = 0.f;
#pragma unroll
    for (int i4 = 0; i4 < 4; i4++) {
        int i = (i4 * 64 + lane) * 4;
        float4 v = *(const float4*)(xr + i);
        bf16x4 b;
        b[0] = (bf16_t)v.x; b[1] = (bf16_t)v.y; b[2] = (bf16_t)v.z; b[3] = (bf16_t)v.w;
        *(bf16x4*)(xbr + i) = b;               // fused fp32->bf16 convert of x
        const float* wr = rw + (size_t)i * NEXP;
#pragma unroll
        for (int e = 0; e < NEXP; e++)
            s[e] += v.x * wr[e] + v.y * wr[NEXP + e] + v.z * wr[2 * NEXP + e]
                  + v.w * wr[3 * NEXP + e];
    }
#pragma unroll
    for (int e = 0; e < NEXP; e++) {
#pragma unroll
        for (int o = 32; o > 0; o >>= 1) s[e] += __shfl_down(s[e], o, 64);
    }
    if (lane == 0) {
        float mx = -1e30f;
#pragma unroll
        for (int e = 0; e < NEXP; e++) { s[e] += rb[e]; mx = fmaxf(mx, s[e]); }
        float den = 0.f;
#pragma unroll
        for (int e = 0; e < NEXP; e++) { s[e] = expf(s[e] - mx); den += s[e]; }
        float inv = 1.f / den;
#pragma unroll
        for (int e = 0; e < NEXP; e++) { s[e] *= inv; probs[t * NEXP + e] = s[e]; }
        int e0 = 0;
#pragma unroll
        for (int e = 1; e < NEXP; e++) if (s[e] > s[e0]) e0 = e;
        int e1 = (e0 == 0) ? 1 : 0;
#pragma unroll
        for (int e = 0; e < NEXP; e++) if (e != e0 && s[e] > s[e1]) e1 = e;
        float sw = s[e0] + s[e1];
        int p0 = atomicAdd(&cnt[e0], 1);
        int p1 = atomicAdd(&cnt[e1], 1);
        tok_e[2 * t] = e0;       tok_e[2 * t + 1] = e1;
        tok_pos[2 * t] = p0;     tok_pos[2 * t + 1] = p1;
        tok_w[2 * t] = s[e0] / sw; tok_w[2 * t + 1] = s[e1] / sw;
    }
}

__global__ void offsets_k(const int* __restrict__ cnt, int* __restrict__ off)
{
    if (threadIdx.x == 0) {
        int a = 0;
        for (int e = 0; e < NEXP; e++) { off[e] = a; a += cnt[e]; }
        off[NEXP] = a;
    }
}

__global__ void scatter_k(const int* __restrict__ tok_e, const int* __restrict__ tok_pos,
                          const float* __restrict__ tok_w, const int* __restrict__ off,
                          int* __restrict__ rows_tok, float* __restrict__ roww,
                          int* __restrict__ g_of)
{
    int i = blockIdx.x * blockDim.x + threadIdx.x;
    if (i < 2 * TOKENS) {
        int e = tok_e[i];
        int g = off[e] + tok_pos[i];
        rows_tok[g] = i >> 1;
        roww[g] = tok_w[i];
        g_of[i] = g;             // token slot -> compact row (for combine)
    }
}

// ---------------- transpose+convert: [E][K][N] f32 -> [E][N][K] bf16 ----------------
// 64x64 tile. float4 global loads (16B/lane), bf16x8 global stores (16B/lane).
// TP=65 pad: both LDS phases land 2-way-per-bank (free, m136).
#define TP 65
__global__ __launch_bounds__(256) void transconv_k(const float* __restrict__ in,
                                                   bf16_t* __restrict__ o, int K, int N)
{
    __shared__ float t[64 * TP];
    int e = blockIdx.z;
    int n0 = blockIdx.x * 64, k0 = blockIdx.y * 64;
    int tid = threadIdx.x;
    int c4 = tid & 15, r = tid >> 4;
    const float* src = in + ((size_t)e * K + k0) * N + n0;
#pragma unroll
    for (int p = 0; p < 4; p++) {
        int k = r + p * 16;
        float4 v = *(const float4*)(src + (size_t)k * N + c4 * 4);
        float* d = &t[k * TP + c4 * 4];
        d[0] = v.x; d[1] = v.y; d[2] = v.z; d[3] = v.w;
    }
    __syncthreads();
    int k8 = tid & 7, n = tid >> 3;
    bf16_t* dst = o + ((size_t)e * N + n0) * K + k0;
#pragma unroll
    for (int p = 0; p < 2; p++) {
        int nn = n + p * 32;
        bf16x8 w;
#pragma unroll
        for (int j = 0; j < 8; j++) w[j] = (bf16_t)t[(k8 * 8 + j) * TP + nn];
        *(bf16x8*)(dst + (size_t)nn * K + k8 * 8) = w;
    }
}

// ---------------- GEMM1: h = gelu(gather(x) @ w1 + b1), 128x128 tile, BK=64 ----
// R0-verified 2-barrier structure (516 TF, MfmaUtil 22%, 0 bank conflicts).
__global__ __launch_bounds__(256, 2) void gemm1_k(
    const bf16_t* __restrict__ A, const bf16_t* __restrict__ Bt,
    const float* __restrict__ bias,
    const int* __restrict__ cnt, const int* __restrict__ off,
    const int* __restrict__ rows_tok, bf16_t* __restrict__ hbuf)
{
    int bid = blockIdx.x;
    int e = bid & 7;
    int rest = bid >> 3;
    int yt = rest & 31;
    int xt = rest >> 5;
    int M = cnt[e];
    int m0 = yt * 128;
    if (m0 >= M) return;
    int n0 = xt * 128;
    int base = off[e];

    __shared__ __align__(16) bf16_t lA[128 * 64];
    __shared__ __align__(16) bf16_t lB[128 * 64];

    int tid = threadIdx.x;
    int wave = tid >> 6;
    int lane = tid & 63;
    int sc = (lane & 7) ^ (lane >> 3);   // XOR swizzle: slot p of row r holds chunk p^(r&7)

    const bf16_t* aRow[4];
    const bf16_t* bRow[4];
#pragma unroll
    for (int i = 0; i < 4; i++) {
        int r = (wave * 4 + i) * 8 + (lane >> 3);
        int gr = m0 + r; if (gr > M - 1) gr = M - 1;
        int tok = rows_tok[base + gr];
        aRow[i] = A + (size_t)tok * DMODEL;
        bRow[i] = Bt + ((size_t)e * DFF + n0 + r) * DMODEL;
    }

    f32x4 acc[4][4];
    f32x4 zero = { 0.f, 0.f, 0.f, 0.f };
#pragma unroll
    for (int i = 0; i < 4; i++)
#pragma unroll
        for (int j = 0; j < 4; j++) acc[i][j] = zero;

    int wrow = wave >> 1, wcol = wave & 1;

#pragma unroll 1
    for (int kk = 0; kk < DMODEL / 64; ++kk) {
        int koff = kk * 64 + sc * 8;
#pragma unroll
        for (int i = 0; i < 4; i++) {
            gl_lds16(aRow[i] + koff, &lA[(wave * 4 + i) * 512]);
            gl_lds16(bRow[i] + koff, &lB[(wave * 4 + i) * 512]);
        }
        __syncthreads();
#pragma unroll
        for (int ks = 0; ks < 2; ++ks) {
            bf16x8 af[4], bfr[4];
#pragma unroll
            for (int mt = 0; mt < 4; mt++) {
                int r = wrow * 64 + mt * 16 + (lane & 15);
                int ch = (ks * 4 + (lane >> 4)) ^ (r & 7);
                af[mt] = *(const bf16x8*)&lA[r * 64 + ch * 8];
            }
#pragma unroll
            for (int nt = 0; nt < 4; nt++) {
                int c = wcol * 64 + nt * 16 + (lane & 15);
                int ch = (ks * 4 + (lane >> 4)) ^ (c & 7);
                bfr[nt] = *(const bf16x8*)&lB[c * 64 + ch * 8];
            }
#pragma unroll
            for (int mt = 0; mt < 4; mt++)
#pragma unroll
                for (int nt = 0; nt < 4; nt++)
                    acc[mt][nt] = __builtin_amdgcn_mfma_f32_16x16x32_bf16(
                        af[mt], bfr[nt], acc[mt][nt], 0, 0, 0);
        }
        __syncthreads();
    }

    // C/D map: col = lane&15, row = (lane>>4)*4 + reg  [m89/m91]
    float bv[4];
#pragma unroll
    for (int nt = 0; nt < 4; nt++)
        bv[nt] = bias[(size_t)e * DFF + n0 + wcol * 64 + nt * 16 + (lane & 15)];

#pragma unroll
    for (int mt = 0; mt < 4; mt++) {
#pragma unroll
        for (int q = 0; q < 4; q++) {
            int r = wrow * 64 + mt * 16 + (lane >> 4) * 4 + q;
            int gm = m0 + r;
            if (gm < M) {
                size_t hrow = (size_t)(base + gm) * DFF;
#pragma unroll
                for (int nt = 0; nt < 4; nt++) {
                    float v = acc[mt][nt][q] + bv[nt];
                    v = 0.5f * v * (1.f + erff(v * 0.70710678118654752f));
                    int c = n0 + wcol * 64 + nt * 16 + (lane & 15);
                    hbuf[hrow + c] = (bf16_t)v;
                }
            }
        }
    }
}

// ---------------- GEMM2: split-K=2 partials, no atomics ----
// ybuf[kt][g][c] = (h[g][kt-half] @ w2[kt-half][c]) as bf16.
// grid: bid&7 = expert; yt fastest, then xt, kt slowest -> per-kt A half-slab
// (4 MB/expert, ~L2) re-read across xt, B panels stream once.
__global__ __launch_bounds__(256, 2) void gemm2_k(
    const bf16_t* __restrict__ A, const bf16_t* __restrict__ Bt,
    const int* __restrict__ cnt, const int* __restrict__ off,
    bf16_t* __restrict__ ybuf)
{
    int bid = blockIdx.x;
    int e = bid & 7;
    int rest = bid >> 3;
    int yt = rest & 31;
    int xt = (rest >> 5) & 7;
    int kt = rest >> 8;
    int M = cnt[e];
    int m0 = yt * 128;
    if (m0 >= M) return;
    int n0 = xt * 128;
    int base = off[e];
    int k0 = kt * (DFF / SPLITK);

    __shared__ __align__(16) bf16_t lA[128 * 64];
    __shared__ __align__(16) bf16_t lB[128 * 64];

    int tid = threadIdx.x;
    int wave = tid >> 6;
    int lane = tid & 63;
    int sc = (lane & 7) ^ (lane >> 3);

    const bf16_t* aRow[4];
    const bf16_t* bRow[4];
#pragma unroll
    for (int i = 0; i < 4; i++) {
        int r = (wave * 4 + i) * 8 + (lane >> 3);
        int gr = m0 + r; if (gr > M - 1) gr = M - 1;
        aRow[i] = A + (size_t)(base + gr) * DFF + k0;
        bRow[i] = Bt + ((size_t)e * DMODEL + n0 + r) * DFF + k0;
    }

    f32x4 acc[4][4];
    f32x4 zero = { 0.f, 0.f, 0.f, 0.f };
#pragma unroll
    for (int i = 0; i < 4; i++)
#pragma unroll
        for (int j = 0; j < 4; j++) acc[i][j] = zero;

    int wrow = wave >> 1, wcol = wave & 1;

#pragma unroll 1
    for (int kk = 0; kk < (DFF / SPLITK) / 64; ++kk) {
        int koff = kk * 64 + sc * 8;
#pragma unroll
        for (int i = 0; i < 4; i++) {
            gl_lds16(aRow[i] + koff, &lA[(wave * 4 + i) * 512]);
            gl_lds16(bRow[i] + koff, &lB[(wave * 4 + i) * 512]);
        }
        __syncthreads();
#pragma unroll
        for (int ks = 0; ks < 2; ++ks) {
            bf16x8 af[4], bfr[4];
#pragma unroll
            for (int mt = 0; mt < 4; mt++) {
                int r = wrow * 64 + mt * 16 + (lane & 15);
                int ch = (ks * 4 + (lane >> 4)) ^ (r & 7);
                af[mt] = *(const bf16x8*)&lA[r * 64 + ch * 8];
            }
#pragma unroll
            for (int nt = 0; nt < 4; nt++) {
                int c = wcol * 64 + nt * 16 + (lane & 15);
                int ch = (ks * 4 + (lane >> 4)) ^ (c & 7);
                bfr[nt] = *(const bf16x8*)&lB[c * 64 + ch * 8];
            }
#pragma unroll
            for (int mt = 0; mt < 4; mt++)
#pragma unroll
                for (int nt = 0; nt < 4; nt++)
                    acc[mt][nt] = __builtin_amdgcn_mfma_f32_16x16x32_bf16(
                        af[mt], bfr[nt], acc[mt][nt], 0, 0, 0);
        }
        __syncthreads();
    }

#pragma unroll
    for (int mt = 0; mt < 4; mt++) {
#pragma unroll
        for (int q = 0; q < 4; q++) {
            int r = wrow * 64 + mt * 16 + (lane >> 4) * 4 + q;
            int gm = m0 + r;
            if (gm < M) {
                size_t yrow = ((size_t)kt * NROWS + base + gm) * DMODEL;
#pragma unroll
                for (int nt = 0; nt < 4; nt++) {
                    int c = n0 + wcol * 64 + nt * 16 + (lane & 15);
                    ybuf[yrow + c] = (bf16_t)acc[mt][nt][q];
                }
            }
        }
    }
}

// ---------------- combine: out[t] = sum_k(w0*(y[g0]+b2[e0]) + w1*(y[g1]+b2[e1])) ----
__global__ __launch_bounds__(256) void combine_k(
    const bf16_t* __restrict__ ybuf, const int* __restrict__ g_of,
    const int* __restrict__ tok_e, const float* __restrict__ tok_w,
    const float* __restrict__ b2, float* __restrict__ out)
{
    int t = blockIdx.x;
    int c = threadIdx.x * 4;
    int g0 = g_of[2 * t], g1 = g_of[2 * t + 1];
    int e0 = tok_e[2 * t], e1 = tok_e[2 * t + 1];
    float w0 = tok_w[2 * t], w1 = tok_w[2 * t + 1];
    float a0[4] = {0.f, 0.f, 0.f, 0.f}, a1[4] = {0.f, 0.f, 0.f, 0.f};
#pragma unroll
    for (int kt = 0; kt < SPLITK; kt++) {
        bf16x4 y0 = *(const bf16x4*)&ybuf[((size_t)kt * NROWS + g0) * DMODEL + c];
        bf16x4 y1 = *(const bf16x4*)&ybuf[((size_t)kt * NROWS + g1) * DMODEL + c];
#pragma unroll
        for (int j = 0; j < 4; j++) { a0[j] += (float)y0[j]; a1[j] += (float)y1[j]; }
    }
    float4 bb0 = *(const float4*)&b2[(size_t)e0 * DMODEL + c];
    float4 bb1 = *(const float4*)&b2[(size_t)e1 * DMODEL + c];
    float4 r;
    r.x = w0 * (a0[0] + bb0.x) + w1 * (a1[0] + bb1.x);
    r.y = w0 * (a0[1] + bb0.y) + w1 * (a1[1] + bb1.y);
    r.z = w0 * (a0[2] + bb0.z) + w1 * (a1[2] + bb1.z);
    r.w = w0 * (a0[3] + bb0.w) + w1 * (a1[3] + bb1.w);
    *(float4*)&out[(size_t)t * DMODEL + c] = r;
}

// ---------------- aux loss: var(mean_probs, ddof=1) ----------------
__global__ __launch_bounds__(256) void aux_k(const float* __restrict__ probs,
                                             float* __restrict__ out_aux)
{
    __shared__ float red[256];
    __shared__ float mexp[NEXP];
    float s[NEXP];
#pragma unroll
    for (int e = 0; e < NEXP; e++) s[e] = 0.f;
    for (int t = threadIdx.x; t < TOKENS; t += 256) {
#pragma unroll
        for (int e = 0; e < NEXP; e++) s[e] += probs[t * NEXP + e];
    }
    for (int e = 0; e < NEXP; e++) {
        red[threadIdx.x] = s[e];
        __syncthreads();
        for (int st = 128; st > 0; st >>= 1) {
            if (threadIdx.x < st) red[threadIdx.x] += red[threadIdx.x + st];
            __syncthreads();
        }
        if (threadIdx.x == 0) mexp[e] = red[0] / (float)TOKENS;
        __syncthreads();
    }
    if (threadIdx.x == 0) {
        float mean = 0.f;
        for (int e = 0; e < NEXP; e++) mean += mexp[e];
        mean /= (float)NEXP;
        float v = 0.f;
        for (int e = 0; e < NEXP; e++) { float d = mexp[e] - mean; v += d * d; }
        out_aux[0] = v / (float)(NEXP - 1);
    }
}

extern "C" void kernel_launch(void* const* d_in, const int* in_sizes, int n_in,
                              void* d_out, int out_size, void* d_ws, size_t ws_size,
                              hipStream_t stream)
{
    const float* x  = (const float*)d_in[0];
    const float* rw = (const float*)d_in[1];
    const float* rb = (const float*)d_in[2];
    const float* w1 = (const float*)d_in[3];
    const float* b1 = (const float*)d_in[4];
    const float* w2 = (const float*)d_in[5];
    const float* b2 = (const float*)d_in[6];
    float* out = (float*)d_out;

    char* p = (char*)d_ws;
    auto alloc = [&](size_t b) { char* q = p; p += (b + 255) & ~(size_t)255; return q; };
    int*    cnt      = (int*)   alloc(NEXP * sizeof(int));
    int*    off      = (int*)   alloc((NEXP + 1) * sizeof(int));
    int*    tok_e    = (int*)   alloc(2 * TOKENS * sizeof(int));
    int*    tok_pos  = (int*)   alloc(2 * TOKENS * sizeof(int));
    float*  tok_w    = (float*) alloc(2 * TOKENS * sizeof(float));
    int*    rows_tok = (int*)   alloc(NROWS * sizeof(int));
    float*  roww     = (float*) alloc(NROWS * sizeof(float));
    int*    g_of     = (int*)   alloc(2 * TOKENS * sizeof(int));
    float*  probs    = (float*) alloc((size_t)TOKENS * NEXP * sizeof(float));
    bf16_t* xb       = (bf16_t*)alloc((size_t)TOKENS * DMODEL * 2);
    bf16_t* w1t      = (bf16_t*)alloc((size_t)NEXP * DFF * DMODEL * 2);
    bf16_t* w2t      = (bf16_t*)alloc((size_t)NEXP * DMODEL * DFF * 2);
    bf16_t* hbuf     = (bf16_t*)alloc((size_t)NROWS * DFF * 2);
    // ybuf (split-K partials, 32 MB at SPLITK=2) aliases w1t: w1t is dead once
    // gemm1 completes, gemm2 runs strictly after on the same stream.
    bf16_t* ybuf     = w1t;

    hipMemsetAsync(cnt, 0, NEXP * sizeof(int), stream);

    router_k<<<TOKENS / 4, 256, 0, stream>>>(x, rw, rb, cnt, tok_e, tok_pos, tok_w, probs, xb);
    offsets_k<<<1, 64, 0, stream>>>(cnt, off);
    scatter_k<<<(2 * TOKENS + 255) / 256, 256, 0, stream>>>(tok_e, tok_pos, tok_w, off,
                                                            rows_tok, roww, g_of);
    transconv_k<<<dim3(DFF / 64, DMODEL / 64, NEXP), 256, 0, stream>>>(w1, w1t, DMODEL, DFF);
    transconv_k<<<dim3(DMODEL / 64, DFF / 64, NEXP), 256, 0, stream>>>(w2, w2t, DFF, DMODEL);

    gemm1_k<<<NEXP * 32 * 32, 256, 0, stream>>>(xb, w1t, b1, cnt, off, rows_tok, hbuf);
    gemm2_k<<<NEXP * 32 * 8 * SPLITK, 256, 0, stream>>>(hbuf, w2t, cnt, off, ybuf);
    combine_k<<<TOKENS, 256, 0, stream>>>(ybuf, g_of, tok_e, tok_w, b2, out);

    aux_k<<<1, 256, 0, stream>>>(probs, out + (size_t)TOKENS * DMODEL);
}

// Round 6
// 647.797 us; speedup vs baseline: 1.1269x; 1.0166x over previous
//
#include <hip/hip_runtime.h>

// Sparse MoE: T=4096 tokens, d=1024, E=8 experts, top-2, ffn=4096.
// route -> compact per-expert row lists (2T rows) -> bf16 MFMA grouped GEMM1
// (gelu) -> GEMM2 split-K=2 (deterministic bf16 partials, no atomics) ->
// combine (token-major weighted sum + bias). Expert e pinned to XCD e via
// bid&7. GEMMs: the R0-verified 2-barrier 128^2 gl_lds structure (516 TF).
// R4: SPLITK 4->2, router 4 tok/block float4 (net ~0 vs baseline).
// R5: transconv retiled 64x64 -> 128Kx64N (256B read AND write segments;
// old wrote 128B segments ~1.9 TB/s effective); aux split into 16-block
// partial + 1-block finish (was a single serial block). GEMMs frozen.

#define TOKENS 4096
#define DMODEL 1024
#define NEXP   8
#define DFF    4096
#define NROWS  (2*TOKENS)
#define SPLITK 2

typedef __bf16 bf16_t;
typedef __bf16 bf16x8 __attribute__((ext_vector_type(8)));
typedef __bf16 bf16x4 __attribute__((ext_vector_type(4)));
typedef float  f32x4  __attribute__((ext_vector_type(4)));

__device__ __forceinline__ void gl_lds16(const void* g, void* l) {
    __builtin_amdgcn_global_load_lds(
        (const __attribute__((address_space(1))) void*)g,
        (__attribute__((address_space(3))) void*)l, 16, 0, 0);
}

// ---------------- router: 4 tokens/block (1 per wave), float4 loads ----------
__global__ __launch_bounds__(256) void router_k(
    const float* __restrict__ x, const float* __restrict__ rw,
    const float* __restrict__ rb, int* __restrict__ cnt,
    int* __restrict__ tok_e, int* __restrict__ tok_pos,
    float* __restrict__ tok_w, float* __restrict__ probs,
    bf16_t* __restrict__ xb)
{
    int w = threadIdx.x >> 6;
    int lane = threadIdx.x & 63;
    int t = blockIdx.x * 4 + w;
    const float* xr = x + (size_t)t * DMODEL;
    bf16_t* xbr = xb + (size_t)t * DMODEL;
    float s[NEXP];
#pragma unroll
    for (int e = 0; e < NEXP; e++) s[e] = 0.f;
#pragma unroll
    for (int i4 = 0; i4 < 4; i4++) {
        int i = (i4 * 64 + lane) * 4;
        float4 v = *(const float4*)(xr + i);
        bf16x4 b;
        b[0] = (bf16_t)v.x; b[1] = (bf16_t)v.y; b[2] = (bf16_t)v.z; b[3] = (bf16_t)v.w;
        *(bf16x4*)(xbr + i) = b;               // fused fp32->bf16 convert of x
        const float* wr = rw + (size_t)i * NEXP;
#pragma unroll
        for (int e = 0; e < NEXP; e++)
            s[e] += v.x * wr[e] + v.y * wr[NEXP + e] + v.z * wr[2 * NEXP + e]
                  + v.w * wr[3 * NEXP + e];
    }
#pragma unroll
    for (int e = 0; e < NEXP; e++) {
#pragma unroll
        for (int o = 32; o > 0; o >>= 1) s[e] += __shfl_down(s[e], o, 64);
    }
    if (lane == 0) {
        float mx = -1e30f;
#pragma unroll
        for (int e = 0; e < NEXP; e++) { s[e] += rb[e]; mx = fmaxf(mx, s[e]); }
        float den = 0.f;
#pragma unroll
        for (int e = 0; e < NEXP; e++) { s[e] = expf(s[e] - mx); den += s[e]; }
        float inv = 1.f / den;
#pragma unroll
        for (int e = 0; e < NEXP; e++) { s[e] *= inv; probs[t * NEXP + e] = s[e]; }
        int e0 = 0;
#pragma unroll
        for (int e = 1; e < NEXP; e++) if (s[e] > s[e0]) e0 = e;
        int e1 = (e0 == 0) ? 1 : 0;
#pragma unroll
        for (int e = 0; e < NEXP; e++) if (e != e0 && s[e] > s[e1]) e1 = e;
        float sw = s[e0] + s[e1];
        int p0 = atomicAdd(&cnt[e0], 1);
        int p1 = atomicAdd(&cnt[e1], 1);
        tok_e[2 * t] = e0;       tok_e[2 * t + 1] = e1;
        tok_pos[2 * t] = p0;     tok_pos[2 * t + 1] = p1;
        tok_w[2 * t] = s[e0] / sw; tok_w[2 * t + 1] = s[e1] / sw;
    }
}

__global__ void offsets_k(const int* __restrict__ cnt, int* __restrict__ off)
{
    if (threadIdx.x == 0) {
        int a = 0;
        for (int e = 0; e < NEXP; e++) { off[e] = a; a += cnt[e]; }
        off[NEXP] = a;
    }
}

__global__ void scatter_k(const int* __restrict__ tok_e, const int* __restrict__ tok_pos,
                          const float* __restrict__ tok_w, const int* __restrict__ off,
                          int* __restrict__ rows_tok, float* __restrict__ roww,
                          int* __restrict__ g_of)
{
    int i = blockIdx.x * blockDim.x + threadIdx.x;
    if (i < 2 * TOKENS) {
        int e = tok_e[i];
        int g = off[e] + tok_pos[i];
        rows_tok[g] = i >> 1;
        roww[g] = tok_w[i];
        g_of[i] = g;             // token slot -> compact row (for combine)
    }
}

// ---------------- transpose+convert: [E][K][N] f32 -> [E][N][K] bf16 ----------------
// R5: 128(K) x 64(N) tile: reads 256B/row AND writes 256B/row (was 128B write
// segments at 64x64). LDS 128x65 f32 = 33 KB -> 4 blocks/CU.
#define TP2 65
__global__ __launch_bounds__(256) void transconv_k(const float* __restrict__ in,
                                                   bf16_t* __restrict__ o, int K, int N)
{
    __shared__ float t[128 * TP2];
    int e = blockIdx.z;
    int n0 = blockIdx.x * 64, k0 = blockIdx.y * 128;
    int tid = threadIdx.x;
    int c4 = (tid & 15) * 4, r = tid >> 4;
    const float* src = in + ((size_t)e * K + k0) * N + n0;
#pragma unroll
    for (int p = 0; p < 8; p++) {
        int k = r + p * 16;
        float4 v = *(const float4*)(src + (size_t)k * N + c4);
        float* d = &t[k * TP2 + c4];
        d[0] = v.x; d[1] = v.y; d[2] = v.z; d[3] = v.w;
    }
    __syncthreads();
    int k8 = tid & 15, n = tid >> 4;
    bf16_t* dst = o + ((size_t)e * N + n0) * K + k0;
#pragma unroll
    for (int p = 0; p < 4; p++) {
        int nn = n + p * 16;
        bf16x8 w;
#pragma unroll
        for (int j = 0; j < 8; j++) w[j] = (bf16_t)t[(k8 * 8 + j) * TP2 + nn];
        *(bf16x8*)(dst + (size_t)nn * K + k8 * 8) = w;
    }
}

// ---------------- GEMM1: h = gelu(gather(x) @ w1 + b1), 128x128 tile, BK=64 ----
// R0-verified 2-barrier structure (516 TF, MfmaUtil 22%, 0 bank conflicts).
__global__ __launch_bounds__(256, 2) void gemm1_k(
    const bf16_t* __restrict__ A, const bf16_t* __restrict__ Bt,
    const float* __restrict__ bias,
    const int* __restrict__ cnt, const int* __restrict__ off,
    const int* __restrict__ rows_tok, bf16_t* __restrict__ hbuf)
{
    int bid = blockIdx.x;
    int e = bid & 7;
    int rest = bid >> 3;
    int yt = rest & 31;
    int xt = rest >> 5;
    int M = cnt[e];
    int m0 = yt * 128;
    if (m0 >= M) return;
    int n0 = xt * 128;
    int base = off[e];

    __shared__ __align__(16) bf16_t lA[128 * 64];
    __shared__ __align__(16) bf16_t lB[128 * 64];

    int tid = threadIdx.x;
    int wave = tid >> 6;
    int lane = tid & 63;
    int sc = (lane & 7) ^ (lane >> 3);   // XOR swizzle: slot p of row r holds chunk p^(r&7)

    const bf16_t* aRow[4];
    const bf16_t* bRow[4];
#pragma unroll
    for (int i = 0; i < 4; i++) {
        int r = (wave * 4 + i) * 8 + (lane >> 3);
        int gr = m0 + r; if (gr > M - 1) gr = M - 1;
        int tok = rows_tok[base + gr];
        aRow[i] = A + (size_t)tok * DMODEL;
        bRow[i] = Bt + ((size_t)e * DFF + n0 + r) * DMODEL;
    }

    f32x4 acc[4][4];
    f32x4 zero = { 0.f, 0.f, 0.f, 0.f };
#pragma unroll
    for (int i = 0; i < 4; i++)
#pragma unroll
        for (int j = 0; j < 4; j++) acc[i][j] = zero;

    int wrow = wave >> 1, wcol = wave & 1;

#pragma unroll 1
    for (int kk = 0; kk < DMODEL / 64; ++kk) {
        int koff = kk * 64 + sc * 8;
#pragma unroll
        for (int i = 0; i < 4; i++) {
            gl_lds16(aRow[i] + koff, &lA[(wave * 4 + i) * 512]);
            gl_lds16(bRow[i] + koff, &lB[(wave * 4 + i) * 512]);
        }
        __syncthreads();
#pragma unroll
        for (int ks = 0; ks < 2; ++ks) {
            bf16x8 af[4], bfr[4];
#pragma unroll
            for (int mt = 0; mt < 4; mt++) {
                int r = wrow * 64 + mt * 16 + (lane & 15);
                int ch = (ks * 4 + (lane >> 4)) ^ (r & 7);
                af[mt] = *(const bf16x8*)&lA[r * 64 + ch * 8];
            }
#pragma unroll
            for (int nt = 0; nt < 4; nt++) {
                int c = wcol * 64 + nt * 16 + (lane & 15);
                int ch = (ks * 4 + (lane >> 4)) ^ (c & 7);
                bfr[nt] = *(const bf16x8*)&lB[c * 64 + ch * 8];
            }
#pragma unroll
            for (int mt = 0; mt < 4; mt++)
#pragma unroll
                for (int nt = 0; nt < 4; nt++)
                    acc[mt][nt] = __builtin_amdgcn_mfma_f32_16x16x32_bf16(
                        af[mt], bfr[nt], acc[mt][nt], 0, 0, 0);
        }
        __syncthreads();
    }

    // C/D map: col = lane&15, row = (lane>>4)*4 + reg  [m89/m91]
    float bv[4];
#pragma unroll
    for (int nt = 0; nt < 4; nt++)
        bv[nt] = bias[(size_t)e * DFF + n0 + wcol * 64 + nt * 16 + (lane & 15)];

#pragma unroll
    for (int mt = 0; mt < 4; mt++) {
#pragma unroll
        for (int q = 0; q < 4; q++) {
            int r = wrow * 64 + mt * 16 + (lane >> 4) * 4 + q;
            int gm = m0 + r;
            if (gm < M) {
                size_t hrow = (size_t)(base + gm) * DFF;
#pragma unroll
                for (int nt = 0; nt < 4; nt++) {
                    float v = acc[mt][nt][q] + bv[nt];
                    v = 0.5f * v * (1.f + erff(v * 0.70710678118654752f));
                    int c = n0 + wcol * 64 + nt * 16 + (lane & 15);
                    hbuf[hrow + c] = (bf16_t)v;
                }
            }
        }
    }
}

// ---------------- GEMM2: split-K=2 partials, no atomics ----
__global__ __launch_bounds__(256, 2) void gemm2_k(
    const bf16_t* __restrict__ A, const bf16_t* __restrict__ Bt,
    const int* __restrict__ cnt, const int* __restrict__ off,
    bf16_t* __restrict__ ybuf)
{
    int bid = blockIdx.x;
    int e = bid & 7;
    int rest = bid >> 3;
    int yt = rest & 31;
    int xt = (rest >> 5) & 7;
    int kt = rest >> 8;
    int M = cnt[e];
    int m0 = yt * 128;
    if (m0 >= M) return;
    int n0 = xt * 128;
    int base = off[e];
    int k0 = kt * (DFF / SPLITK);

    __shared__ __align__(16) bf16_t lA[128 * 64];
    __shared__ __align__(16) bf16_t lB[128 * 64];

    int tid = threadIdx.x;
    int wave = tid >> 6;
    int lane = tid & 63;
    int sc = (lane & 7) ^ (lane >> 3);

    const bf16_t* aRow[4];
    const bf16_t* bRow[4];
#pragma unroll
    for (int i = 0; i < 4; i++) {
        int r = (wave * 4 + i) * 8 + (lane >> 3);
        int gr = m0 + r; if (gr > M - 1) gr = M - 1;
        aRow[i] = A + (size_t)(base + gr) * DFF + k0;
        bRow[i] = Bt + ((size_t)e * DMODEL + n0 + r) * DFF + k0;
    }

    f32x4 acc[4][4];
    f32x4 zero = { 0.f, 0.f, 0.f, 0.f };
#pragma unroll
    for (int i = 0; i < 4; i++)
#pragma unroll
        for (int j = 0; j < 4; j++) acc[i][j] = zero;

    int wrow = wave >> 1, wcol = wave & 1;

#pragma unroll 1
    for (int kk = 0; kk < (DFF / SPLITK) / 64; ++kk) {
        int koff = kk * 64 + sc * 8;
#pragma unroll
        for (int i = 0; i < 4; i++) {
            gl_lds16(aRow[i] + koff, &lA[(wave * 4 + i) * 512]);
            gl_lds16(bRow[i] + koff, &lB[(wave * 4 + i) * 512]);
        }
        __syncthreads();
#pragma unroll
        for (int ks = 0; ks < 2; ++ks) {
            bf16x8 af[4], bfr[4];
#pragma unroll
            for (int mt = 0; mt < 4; mt++) {
                int r = wrow * 64 + mt * 16 + (lane & 15);
                int ch = (ks * 4 + (lane >> 4)) ^ (r & 7);
                af[mt] = *(const bf16x8*)&lA[r * 64 + ch * 8];
            }
#pragma unroll
            for (int nt = 0; nt < 4; nt++) {
                int c = wcol * 64 + nt * 16 + (lane & 15);
                int ch = (ks * 4 + (lane >> 4)) ^ (c & 7);
                bfr[nt] = *(const bf16x8*)&lB[c * 64 + ch * 8];
            }
#pragma unroll
            for (int mt = 0; mt < 4; mt++)
#pragma unroll
                for (int nt = 0; nt < 4; nt++)
                    acc[mt][nt] = __builtin_amdgcn_mfma_f32_16x16x32_bf16(
                        af[mt], bfr[nt], acc[mt][nt], 0, 0, 0);
        }
        __syncthreads();
    }

#pragma unroll
    for (int mt = 0; mt < 4; mt++) {
#pragma unroll
        for (int q = 0; q < 4; q++) {
            int r = wrow * 64 + mt * 16 + (lane >> 4) * 4 + q;
            int gm = m0 + r;
            if (gm < M) {
                size_t yrow = ((size_t)kt * NROWS + base + gm) * DMODEL;
#pragma unroll
                for (int nt = 0; nt < 4; nt++) {
                    int c = n0 + wcol * 64 + nt * 16 + (lane & 15);
                    ybuf[yrow + c] = (bf16_t)acc[mt][nt][q];
                }
            }
        }
    }
}

// ---------------- combine: out[t] = sum_k(w0*(y[g0]+b2[e0]) + w1*(y[g1]+b2[e1])) ----
__global__ __launch_bounds__(256) void combine_k(
    const bf16_t* __restrict__ ybuf, const int* __restrict__ g_of,
    const int* __restrict__ tok_e, const float* __restrict__ tok_w,
    const float* __restrict__ b2, float* __restrict__ out)
{
    int t = blockIdx.x;
    int c = threadIdx.x * 4;
    int g0 = g_of[2 * t], g1 = g_of[2 * t + 1];
    int e0 = tok_e[2 * t], e1 = tok_e[2 * t + 1];
    float w0 = tok_w[2 * t], w1 = tok_w[2 * t + 1];
    float a0[4] = {0.f, 0.f, 0.f, 0.f}, a1[4] = {0.f, 0.f, 0.f, 0.f};
#pragma unroll
    for (int kt = 0; kt < SPLITK; kt++) {
        bf16x4 y0 = *(const bf16x4*)&ybuf[((size_t)kt * NROWS + g0) * DMODEL + c];
        bf16x4 y1 = *(const bf16x4*)&ybuf[((size_t)kt * NROWS + g1) * DMODEL + c];
#pragma unroll
        for (int j = 0; j < 4; j++) { a0[j] += (float)y0[j]; a1[j] += (float)y1[j]; }
    }
    float4 bb0 = *(const float4*)&b2[(size_t)e0 * DMODEL + c];
    float4 bb1 = *(const float4*)&b2[(size_t)e1 * DMODEL + c];
    float4 r;
    r.x = w0 * (a0[0] + bb0.x) + w1 * (a1[0] + bb1.x);
    r.y = w0 * (a0[1] + bb0.y) + w1 * (a1[1] + bb1.y);
    r.z = w0 * (a0[2] + bb0.z) + w1 * (a1[2] + bb1.z);
    r.w = w0 * (a0[3] + bb0.w) + w1 * (a1[3] + bb1.w);
    *(float4*)&out[(size_t)t * DMODEL + c] = r;
}

// ---------------- aux loss: var(mean_probs, ddof=1), 2-stage deterministic ----
__global__ __launch_bounds__(256) void aux1_k(const float* __restrict__ probs,
                                              float* __restrict__ partial)
{
    int t = blockIdx.x * 256 + threadIdx.x;
    const float4* pr = (const float4*)(probs + (size_t)t * NEXP);
    float4 a = pr[0], b = pr[1];
    float v[8] = { a.x, a.y, a.z, a.w, b.x, b.y, b.z, b.w };
#pragma unroll
    for (int e = 0; e < 8; e++)
#pragma unroll
        for (int o = 32; o > 0; o >>= 1) v[e] += __shfl_down(v[e], o, 64);
    __shared__ float sm[4][8];
    int wave = threadIdx.x >> 6, lane = threadIdx.x & 63;
    if (lane == 0)
#pragma unroll
        for (int e = 0; e < 8; e++) sm[wave][e] = v[e];
    __syncthreads();
    if (threadIdx.x < 8) {
        float s = sm[0][threadIdx.x] + sm[1][threadIdx.x]
                + sm[2][threadIdx.x] + sm[3][threadIdx.x];
        partial[blockIdx.x * 8 + threadIdx.x] = s;
    }
}

__global__ __launch_bounds__(128) void aux2_k(const float* __restrict__ partial,
                                              float* __restrict__ out_aux)
{
    __shared__ float sm[16][8];
    __shared__ float me[8];
    int tid = threadIdx.x;
    sm[tid >> 3][tid & 7] = partial[tid];
    __syncthreads();
    if (tid < 8) {
        float s = 0.f;
        for (int g = 0; g < 16; g++) s += sm[g][tid];
        me[tid] = s / (float)TOKENS;
    }
    __syncthreads();
    if (tid == 0) {
        float mean = 0.f;
        for (int e = 0; e < 8; e++) mean += me[e];
        mean /= 8.f;
        float v = 0.f;
        for (int e = 0; e < 8; e++) { float d = me[e] - mean; v += d * d; }
        out_aux[0] = v / 7.f;
    }
}

extern "C" void kernel_launch(void* const* d_in, const int* in_sizes, int n_in,
                              void* d_out, int out_size, void* d_ws, size_t ws_size,
                              hipStream_t stream)
{
    const float* x  = (const float*)d_in[0];
    const float* rw = (const float*)d_in[1];
    const float* rb = (const float*)d_in[2];
    const float* w1 = (const float*)d_in[3];
    const float* b1 = (const float*)d_in[4];
    const float* w2 = (const float*)d_in[5];
    const float* b2 = (const float*)d_in[6];
    float* out = (float*)d_out;

    char* p = (char*)d_ws;
    auto alloc = [&](size_t b) { char* q = p; p += (b + 255) & ~(size_t)255; return q; };
    int*    cnt      = (int*)   alloc(NEXP * sizeof(int));
    int*    off      = (int*)   alloc((NEXP + 1) * sizeof(int));
    int*    tok_e    = (int*)   alloc(2 * TOKENS * sizeof(int));
    int*    tok_pos  = (int*)   alloc(2 * TOKENS * sizeof(int));
    float*  tok_w    = (float*) alloc(2 * TOKENS * sizeof(float));
    int*    rows_tok = (int*)   alloc(NROWS * sizeof(int));
    float*  roww     = (float*) alloc(NROWS * sizeof(float));
    int*    g_of     = (int*)   alloc(2 * TOKENS * sizeof(int));
    float*  probs    = (float*) alloc((size_t)TOKENS * NEXP * sizeof(float));
    float*  aux_part = (float*) alloc(16 * NEXP * sizeof(float));
    bf16_t* xb       = (bf16_t*)alloc((size_t)TOKENS * DMODEL * 2);
    bf16_t* w1t      = (bf16_t*)alloc((size_t)NEXP * DFF * DMODEL * 2);
    bf16_t* w2t      = (bf16_t*)alloc((size_t)NEXP * DMODEL * DFF * 2);
    bf16_t* hbuf     = (bf16_t*)alloc((size_t)NROWS * DFF * 2);
    // ybuf (split-K partials, 32 MB at SPLITK=2) aliases w1t: w1t is dead once
    // gemm1 completes, gemm2 runs strictly after on the same stream.
    bf16_t* ybuf     = w1t;

    hipMemsetAsync(cnt, 0, NEXP * sizeof(int), stream);

    router_k<<<TOKENS / 4, 256, 0, stream>>>(x, rw, rb, cnt, tok_e, tok_pos, tok_w, probs, xb);
    offsets_k<<<1, 64, 0, stream>>>(cnt, off);
    scatter_k<<<(2 * TOKENS + 255) / 256, 256, 0, stream>>>(tok_e, tok_pos, tok_w, off,
                                                            rows_tok, roww, g_of);
    transconv_k<<<dim3(DFF / 64, DMODEL / 128, NEXP), 256, 0, stream>>>(w1, w1t, DMODEL, DFF);
    transconv_k<<<dim3(DMODEL / 64, DFF / 128, NEXP), 256, 0, stream>>>(w2, w2t, DFF, DMODEL);

    gemm1_k<<<NEXP * 32 * 32, 256, 0, stream>>>(xb, w1t, b1, cnt, off, rows_tok, hbuf);
    gemm2_k<<<NEXP * 32 * 8 * SPLITK, 256, 0, stream>>>(hbuf, w2t, cnt, off, ybuf);
    combine_k<<<TOKENS, 256, 0, stream>>>(ybuf, g_of, tok_e, tok_w, b2, out);

    aux1_k<<<TOKENS / 256, 256, 0, stream>>>(probs, aux_part);
    aux2_k<<<1, 128, 0, stream>>>(aux_part, out + (size_t)TOKENS * DMODEL);
}

// Round 7
// 578.226 us; speedup vs baseline: 1.2624x; 1.1203x over previous
//
#include <hip/hip_runtime.h>

// Sparse MoE: T=4096 tokens, d=1024, E=8 experts, top-2, ffn=4096.
// route -> compact per-expert row lists -> bf16 MFMA grouped GEMM1 (gelu) ->
// GEMM2 split-K=2 (deterministic bf16 partials) -> combine.
// R6: horizontal fusion to overlap independent DAG branches (no events in
// graph capture -> one grid, block-level branch):
//  * transconv_w2 (only needed by gemm2) interleaved INTO gemm1's dispatch,
//    period 24 = 16 gemm1 + 8 tc; gemm1 keeps e=bid&7 XCD pinning (P&7 over
//    positions 0..15 covers each XCD exactly 2x; (e,yt,xt) coverage bijective).
//    gemm1 is latency-bound (HBM 11%, MFMA 22%) -> tc streams in its bubbles.
//  * transconv_w1 interleaved into router (period 5 = 4 tc + 1 router).
//  * offsets+scatter merged to one 1-block kernel; aux1 appended to combine.
//  10 -> 7 launches. GEMM inner loops byte-identical to the verified R0 code.

#define TOKENS 4096
#define DMODEL 1024
#define NEXP   8
#define DFF    4096
#define NROWS  (2*TOKENS)
#define SPLITK 2
#define TP2    65

typedef __bf16 bf16_t;
typedef __bf16 bf16x8 __attribute__((ext_vector_type(8)));
typedef __bf16 bf16x4 __attribute__((ext_vector_type(4)));
typedef float  f32x4  __attribute__((ext_vector_type(4)));

__device__ __forceinline__ void gl_lds16(const void* g, void* l) {
    __builtin_amdgcn_global_load_lds(
        (const __attribute__((address_space(1))) void*)g,
        (__attribute__((address_space(3))) void*)l, 16, 0, 0);
}

// ---------------- transpose+convert device body: [e][K][N] f32 -> [e][N][K] bf16 ----
// 128(K) x 64(N) tile; 256B read and write segments; LDS 128x65 f32.
__device__ __forceinline__ void transconv_dev(const float* __restrict__ in,
                                              bf16_t* __restrict__ o, int K, int N,
                                              int xg, int yg, int e, float* t, int tid)
{
    int n0 = xg * 64, k0 = yg * 128;
    int c4 = (tid & 15) * 4, r = tid >> 4;
    const float* src = in + ((size_t)e * K + k0) * N + n0;
#pragma unroll
    for (int p = 0; p < 8; p++) {
        int k = r + p * 16;
        float4 v = *(const float4*)(src + (size_t)k * N + c4);
        float* d = &t[k * TP2 + c4];
        d[0] = v.x; d[1] = v.y; d[2] = v.z; d[3] = v.w;
    }
    __syncthreads();
    int k8 = tid & 15, n = tid >> 4;
    bf16_t* dst = o + ((size_t)e * N + n0) * K + k0;
#pragma unroll
    for (int p = 0; p < 4; p++) {
        int nn = n + p * 16;
        bf16x8 w;
#pragma unroll
        for (int j = 0; j < 8; j++) w[j] = (bf16_t)t[(k8 * 8 + j) * TP2 + nn];
        *(bf16x8*)(dst + (size_t)nn * K + k8 * 8) = w;
    }
}

// ---------------- fused router (4 tok/block) + transconv_w1 ----------------
// period 5: P<4 -> tc_w1 block idx=C*4+P (4096 total); P==4 -> router block C.
__global__ __launch_bounds__(256) void router_tw1_k(
    const float* __restrict__ x, const float* __restrict__ rw,
    const float* __restrict__ rb, int* __restrict__ cnt,
    int* __restrict__ tok_e, int* __restrict__ tok_pos,
    float* __restrict__ tok_w, float* __restrict__ probs,
    bf16_t* __restrict__ xb,
    const float* __restrict__ w1, bf16_t* __restrict__ w1t)
{
    __shared__ __align__(16) char smem[128 * TP2 * 4];
    int P = blockIdx.x % 5, C = blockIdx.x / 5;
    int tid = threadIdx.x;
    if (P < 4) {
        int idx = C * 4 + P;                  // [0,4096)
        int xg = idx & 63;                    // DFF/64
        int yg = (idx >> 6) & 7;              // DMODEL/128
        int eg = idx >> 9;
        transconv_dev(w1, w1t, DMODEL, DFF, xg, yg, eg, (float*)smem, tid);
        return;
    }
    int w = tid >> 6;
    int lane = tid & 63;
    int t = C * 4 + w;
    const float* xr = x + (size_t)t * DMODEL;
    bf16_t* xbr = xb + (size_t)t * DMODEL;
    float s[NEXP];
#pragma unroll
    for (int e = 0; e < NEXP; e++) s[e] = 0.f;
#pragma unroll
    for (int i4 = 0; i4 < 4; i4++) {
        int i = (i4 * 64 + lane) * 4;
        float4 v = *(const float4*)(xr + i);
        bf16x4 b;
        b[0] = (bf16_t)v.x; b[1] = (bf16_t)v.y; b[2] = (bf16_t)v.z; b[3] = (bf16_t)v.w;
        *(bf16x4*)(xbr + i) = b;               // fused fp32->bf16 convert of x
        const float* wr = rw + (size_t)i * NEXP;
#pragma unroll
        for (int e = 0; e < NEXP; e++)
            s[e] += v.x * wr[e] + v.y * wr[NEXP + e] + v.z * wr[2 * NEXP + e]
                  + v.w * wr[3 * NEXP + e];
    }
#pragma unroll
    for (int e = 0; e < NEXP; e++) {
#pragma unroll
        for (int o = 32; o > 0; o >>= 1) s[e] += __shfl_down(s[e], o, 64);
    }
    if (lane == 0) {
        float mx = -1e30f;
#pragma unroll
        for (int e = 0; e < NEXP; e++) { s[e] += rb[e]; mx = fmaxf(mx, s[e]); }
        float den = 0.f;
#pragma unroll
        for (int e = 0; e < NEXP; e++) { s[e] = expf(s[e] - mx); den += s[e]; }
        float inv = 1.f / den;
#pragma unroll
        for (int e = 0; e < NEXP; e++) { s[e] *= inv; probs[t * NEXP + e] = s[e]; }
        int e0 = 0;
#pragma unroll
        for (int e = 1; e < NEXP; e++) if (s[e] > s[e0]) e0 = e;
        int e1 = (e0 == 0) ? 1 : 0;
#pragma unroll
        for (int e = 0; e < NEXP; e++) if (e != e0 && s[e] > s[e1]) e1 = e;
        float sw = s[e0] + s[e1];
        int p0 = atomicAdd(&cnt[e0], 1);
        int p1 = atomicAdd(&cnt[e1], 1);
        tok_e[2 * t] = e0;       tok_e[2 * t + 1] = e1;
        tok_pos[2 * t] = p0;     tok_pos[2 * t + 1] = p1;
        tok_w[2 * t] = s[e0] / sw; tok_w[2 * t + 1] = s[e1] / sw;
    }
}

// ---------------- offsets + scatter, one block ----------------
__global__ __launch_bounds__(256) void offsets_scatter_k(
    const int* __restrict__ cnt, int* __restrict__ off,
    const int* __restrict__ tok_e, const int* __restrict__ tok_pos,
    const float* __restrict__ tok_w,
    int* __restrict__ rows_tok, float* __restrict__ roww, int* __restrict__ g_of)
{
    __shared__ int soff[NEXP];
    if (threadIdx.x == 0) {
        int a = 0;
        for (int e = 0; e < NEXP; e++) { soff[e] = a; off[e] = a; a += cnt[e]; }
        off[NEXP] = a;
    }
    __syncthreads();
    for (int i = threadIdx.x; i < 2 * TOKENS; i += 256) {
        int e = tok_e[i];
        int g = soff[e] + tok_pos[i];
        rows_tok[g] = i >> 1;
        roww[g] = tok_w[i];
        g_of[i] = g;             // token slot -> compact row (for combine)
    }
}

// ---------------- fused GEMM1 (gelu epilogue) + transconv_w2 ----------------
// period 24: P<16 -> gemm1 (e=P&7=bid&7 XCD pin preserved; local=C*2+(P>>3),
// yt=local&31 fastest, xt=local>>5); P>=16 -> tc_w2 idx=C*8+(P-16) (4096).
__global__ __launch_bounds__(256, 2) void gemm1_tw2_k(
    const bf16_t* __restrict__ A, const bf16_t* __restrict__ Bt,
    const float* __restrict__ bias,
    const int* __restrict__ cnt, const int* __restrict__ off,
    const int* __restrict__ rows_tok, bf16_t* __restrict__ hbuf,
    const float* __restrict__ w2, bf16_t* __restrict__ w2t)
{
    __shared__ __align__(16) char smem[128 * TP2 * 4];   // 33280 B (gemm1 uses 32768)
    int P = blockIdx.x % 24, C = blockIdx.x / 24;
    int tid = threadIdx.x;
    if (P >= 16) {
        int idx = C * 8 + (P - 16);           // [0,4096)
        int xg = idx & 15;                    // DMODEL/64
        int yg = (idx >> 4) & 31;             // DFF/128
        int eg = idx >> 9;
        transconv_dev(w2, w2t, DFF, DMODEL, xg, yg, eg, (float*)smem, tid);
        return;
    }
    int e = P & 7;                            // == bid&7 (24%8==0): XCD pin
    int local = C * 2 + (P >> 3);             // [0,1024) per expert
    int yt = local & 31;
    int xt = local >> 5;
    int M = cnt[e];
    int m0 = yt * 128;
    if (m0 >= M) return;
    int n0 = xt * 128;
    int base = off[e];

    bf16_t* lA = (bf16_t*)smem;
    bf16_t* lB = lA + 128 * 64;

    int wave = tid >> 6;
    int lane = tid & 63;
    int sc = (lane & 7) ^ (lane >> 3);   // XOR swizzle: slot p of row r holds chunk p^(r&7)

    const bf16_t* aRow[4];
    const bf16_t* bRow[4];
#pragma unroll
    for (int i = 0; i < 4; i++) {
        int r = (wave * 4 + i) * 8 + (lane >> 3);
        int gr = m0 + r; if (gr > M - 1) gr = M - 1;
        int tok = rows_tok[base + gr];
        aRow[i] = A + (size_t)tok * DMODEL;
        bRow[i] = Bt + ((size_t)e * DFF + n0 + r) * DMODEL;
    }

    f32x4 acc[4][4];
    f32x4 zero = { 0.f, 0.f, 0.f, 0.f };
#pragma unroll
    for (int i = 0; i < 4; i++)
#pragma unroll
        for (int j = 0; j < 4; j++) acc[i][j] = zero;

    int wrow = wave >> 1, wcol = wave & 1;

#pragma unroll 1
    for (int kk = 0; kk < DMODEL / 64; ++kk) {
        int koff = kk * 64 + sc * 8;
#pragma unroll
        for (int i = 0; i < 4; i++) {
            gl_lds16(aRow[i] + koff, &lA[(wave * 4 + i) * 512]);
            gl_lds16(bRow[i] + koff, &lB[(wave * 4 + i) * 512]);
        }
        __syncthreads();
#pragma unroll
        for (int ks = 0; ks < 2; ++ks) {
            bf16x8 af[4], bfr[4];
#pragma unroll
            for (int mt = 0; mt < 4; mt++) {
                int r = wrow * 64 + mt * 16 + (lane & 15);
                int ch = (ks * 4 + (lane >> 4)) ^ (r & 7);
                af[mt] = *(const bf16x8*)&lA[r * 64 + ch * 8];
            }
#pragma unroll
            for (int nt = 0; nt < 4; nt++) {
                int c = wcol * 64 + nt * 16 + (lane & 15);
                int ch = (ks * 4 + (lane >> 4)) ^ (c & 7);
                bfr[nt] = *(const bf16x8*)&lB[c * 64 + ch * 8];
            }
#pragma unroll
            for (int mt = 0; mt < 4; mt++)
#pragma unroll
                for (int nt = 0; nt < 4; nt++)
                    acc[mt][nt] = __builtin_amdgcn_mfma_f32_16x16x32_bf16(
                        af[mt], bfr[nt], acc[mt][nt], 0, 0, 0);
        }
        __syncthreads();
    }

    // C/D map: col = lane&15, row = (lane>>4)*4 + reg  [m89/m91]
    float bv[4];
#pragma unroll
    for (int nt = 0; nt < 4; nt++)
        bv[nt] = bias[(size_t)e * DFF + n0 + wcol * 64 + nt * 16 + (lane & 15)];

#pragma unroll
    for (int mt = 0; mt < 4; mt++) {
#pragma unroll
        for (int q = 0; q < 4; q++) {
            int r = wrow * 64 + mt * 16 + (lane >> 4) * 4 + q;
            int gm = m0 + r;
            if (gm < M) {
                size_t hrow = (size_t)(base + gm) * DFF;
#pragma unroll
                for (int nt = 0; nt < 4; nt++) {
                    float v = acc[mt][nt][q] + bv[nt];
                    v = 0.5f * v * (1.f + erff(v * 0.70710678118654752f));
                    int c = n0 + wcol * 64 + nt * 16 + (lane & 15);
                    hbuf[hrow + c] = (bf16_t)v;
                }
            }
        }
    }
}

// ---------------- GEMM2: split-K=2 partials, no atomics ----
__global__ __launch_bounds__(256, 2) void gemm2_k(
    const bf16_t* __restrict__ A, const bf16_t* __restrict__ Bt,
    const int* __restrict__ cnt, const int* __restrict__ off,
    bf16_t* __restrict__ ybuf)
{
    int bid = blockIdx.x;
    int e = bid & 7;
    int rest = bid >> 3;
    int yt = rest & 31;
    int xt = (rest >> 5) & 7;
    int kt = rest >> 8;
    int M = cnt[e];
    int m0 = yt * 128;
    if (m0 >= M) return;
    int n0 = xt * 128;
    int base = off[e];
    int k0 = kt * (DFF / SPLITK);

    __shared__ __align__(16) bf16_t lA[128 * 64];
    __shared__ __align__(16) bf16_t lB[128 * 64];

    int tid = threadIdx.x;
    int wave = tid >> 6;
    int lane = tid & 63;
    int sc = (lane & 7) ^ (lane >> 3);

    const bf16_t* aRow[4];
    const bf16_t* bRow[4];
#pragma unroll
    for (int i = 0; i < 4; i++) {
        int r = (wave * 4 + i) * 8 + (lane >> 3);
        int gr = m0 + r; if (gr > M - 1) gr = M - 1;
        aRow[i] = A + (size_t)(base + gr) * DFF + k0;
        bRow[i] = Bt + ((size_t)e * DMODEL + n0 + r) * DFF + k0;
    }

    f32x4 acc[4][4];
    f32x4 zero = { 0.f, 0.f, 0.f, 0.f };
#pragma unroll
    for (int i = 0; i < 4; i++)
#pragma unroll
        for (int j = 0; j < 4; j++) acc[i][j] = zero;

    int wrow = wave >> 1, wcol = wave & 1;

#pragma unroll 1
    for (int kk = 0; kk < (DFF / SPLITK) / 64; ++kk) {
        int koff = kk * 64 + sc * 8;
#pragma unroll
        for (int i = 0; i < 4; i++) {
            gl_lds16(aRow[i] + koff, &lA[(wave * 4 + i) * 512]);
            gl_lds16(bRow[i] + koff, &lB[(wave * 4 + i) * 512]);
        }
        __syncthreads();
#pragma unroll
        for (int ks = 0; ks < 2; ++ks) {
            bf16x8 af[4], bfr[4];
#pragma unroll
            for (int mt = 0; mt < 4; mt++) {
                int r = wrow * 64 + mt * 16 + (lane & 15);
                int ch = (ks * 4 + (lane >> 4)) ^ (r & 7);
                af[mt] = *(const bf16x8*)&lA[r * 64 + ch * 8];
            }
#pragma unroll
            for (int nt = 0; nt < 4; nt++) {
                int c = wcol * 64 + nt * 16 + (lane & 15);
                int ch = (ks * 4 + (lane >> 4)) ^ (c & 7);
                bfr[nt] = *(const bf16x8*)&lB[c * 64 + ch * 8];
            }
#pragma unroll
            for (int mt = 0; mt < 4; mt++)
#pragma unroll
                for (int nt = 0; nt < 4; nt++)
                    acc[mt][nt] = __builtin_amdgcn_mfma_f32_16x16x32_bf16(
                        af[mt], bfr[nt], acc[mt][nt], 0, 0, 0);
        }
        __syncthreads();
    }

#pragma unroll
    for (int mt = 0; mt < 4; mt++) {
#pragma unroll
        for (int q = 0; q < 4; q++) {
            int r = wrow * 64 + mt * 16 + (lane >> 4) * 4 + q;
            int gm = m0 + r;
            if (gm < M) {
                size_t yrow = ((size_t)kt * NROWS + base + gm) * DMODEL;
#pragma unroll
                for (int nt = 0; nt < 4; nt++) {
                    int c = n0 + wcol * 64 + nt * 16 + (lane & 15);
                    ybuf[yrow + c] = (bf16_t)acc[mt][nt][q];
                }
            }
        }
    }
}

// ---------------- fused combine + aux1 ----------------
__global__ __launch_bounds__(256) void combine_aux1_k(
    const bf16_t* __restrict__ ybuf, const int* __restrict__ g_of,
    const int* __restrict__ tok_e, const float* __restrict__ tok_w,
    const float* __restrict__ b2, float* __restrict__ out,
    const float* __restrict__ probs, float* __restrict__ partial)
{
    __shared__ float sm[4][8];
    if (blockIdx.x >= TOKENS) {
        // aux1 branch: 16 blocks, each reduces 256 tokens' probs
        int blk = blockIdx.x - TOKENS;
        int t = blk * 256 + threadIdx.x;
        const float4* pr = (const float4*)(probs + (size_t)t * NEXP);
        float4 a = pr[0], b = pr[1];
        float v[8] = { a.x, a.y, a.z, a.w, b.x, b.y, b.z, b.w };
#pragma unroll
        for (int e = 0; e < 8; e++)
#pragma unroll
            for (int o = 32; o > 0; o >>= 1) v[e] += __shfl_down(v[e], o, 64);
        int wave = threadIdx.x >> 6, lane = threadIdx.x & 63;
        if (lane == 0)
#pragma unroll
            for (int e = 0; e < 8; e++) sm[wave][e] = v[e];
        __syncthreads();
        if (threadIdx.x < 8) {
            float s = sm[0][threadIdx.x] + sm[1][threadIdx.x]
                    + sm[2][threadIdx.x] + sm[3][threadIdx.x];
            partial[blk * 8 + threadIdx.x] = s;
        }
        return;
    }
    int t = blockIdx.x;
    int c = threadIdx.x * 4;
    int g0 = g_of[2 * t], g1 = g_of[2 * t + 1];
    int e0 = tok_e[2 * t], e1 = tok_e[2 * t + 1];
    float w0 = tok_w[2 * t], w1 = tok_w[2 * t + 1];
    float a0[4] = {0.f, 0.f, 0.f, 0.f}, a1[4] = {0.f, 0.f, 0.f, 0.f};
#pragma unroll
    for (int kt = 0; kt < SPLITK; kt++) {
        bf16x4 y0 = *(const bf16x4*)&ybuf[((size_t)kt * NROWS + g0) * DMODEL + c];
        bf16x4 y1 = *(const bf16x4*)&ybuf[((size_t)kt * NROWS + g1) * DMODEL + c];
#pragma unroll
        for (int j = 0; j < 4; j++) { a0[j] += (float)y0[j]; a1[j] += (float)y1[j]; }
    }
    float4 bb0 = *(const float4*)&b2[(size_t)e0 * DMODEL + c];
    float4 bb1 = *(const float4*)&b2[(size_t)e1 * DMODEL + c];
    float4 r;
    r.x = w0 * (a0[0] + bb0.x) + w1 * (a1[0] + bb1.x);
    r.y = w0 * (a0[1] + bb0.y) + w1 * (a1[1] + bb1.y);
    r.z = w0 * (a0[2] + bb0.z) + w1 * (a1[2] + bb1.z);
    r.w = w0 * (a0[3] + bb0.w) + w1 * (a1[3] + bb1.w);
    *(float4*)&out[(size_t)t * DMODEL + c] = r;
}

__global__ __launch_bounds__(128) void aux2_k(const float* __restrict__ partial,
                                              float* __restrict__ out_aux)
{
    __shared__ float sm[16][8];
    __shared__ float me[8];
    int tid = threadIdx.x;
    sm[tid >> 3][tid & 7] = partial[tid];
    __syncthreads();
    if (tid < 8) {
        float s = 0.f;
        for (int g = 0; g < 16; g++) s += sm[g][tid];
        me[tid] = s / (float)TOKENS;
    }
    __syncthreads();
    if (tid == 0) {
        float mean = 0.f;
        for (int e = 0; e < 8; e++) mean += me[e];
        mean /= 8.f;
        float v = 0.f;
        for (int e = 0; e < 8; e++) { float d = me[e] - mean; v += d * d; }
        out_aux[0] = v / 7.f;
    }
}

extern "C" void kernel_launch(void* const* d_in, const int* in_sizes, int n_in,
                              void* d_out, int out_size, void* d_ws, size_t ws_size,
                              hipStream_t stream)
{
    const float* x  = (const float*)d_in[0];
    const float* rw = (const float*)d_in[1];
    const float* rb = (const float*)d_in[2];
    const float* w1 = (const float*)d_in[3];
    const float* b1 = (const float*)d_in[4];
    const float* w2 = (const float*)d_in[5];
    const float* b2 = (const float*)d_in[6];
    float* out = (float*)d_out;

    char* p = (char*)d_ws;
    auto alloc = [&](size_t b) { char* q = p; p += (b + 255) & ~(size_t)255; return q; };
    int*    cnt      = (int*)   alloc(NEXP * sizeof(int));
    int*    off      = (int*)   alloc((NEXP + 1) * sizeof(int));
    int*    tok_e    = (int*)   alloc(2 * TOKENS * sizeof(int));
    int*    tok_pos  = (int*)   alloc(2 * TOKENS * sizeof(int));
    float*  tok_w    = (float*) alloc(2 * TOKENS * sizeof(float));
    int*    rows_tok = (int*)   alloc(NROWS * sizeof(int));
    float*  roww     = (float*) alloc(NROWS * sizeof(float));
    int*    g_of     = (int*)   alloc(2 * TOKENS * sizeof(int));
    float*  probs    = (float*) alloc((size_t)TOKENS * NEXP * sizeof(float));
    float*  aux_part = (float*) alloc(16 * NEXP * sizeof(float));
    bf16_t* xb       = (bf16_t*)alloc((size_t)TOKENS * DMODEL * 2);
    bf16_t* w1t      = (bf16_t*)alloc((size_t)NEXP * DFF * DMODEL * 2);
    bf16_t* w2t      = (bf16_t*)alloc((size_t)NEXP * DMODEL * DFF * 2);
    bf16_t* hbuf     = (bf16_t*)alloc((size_t)NROWS * DFF * 2);
    // ybuf (split-K partials, 32 MB at SPLITK=2) aliases w1t: w1t is dead once
    // gemm1 completes, gemm2 runs strictly after on the same stream.
    bf16_t* ybuf     = w1t;

    hipMemsetAsync(cnt, 0, NEXP * sizeof(int), stream);

    // router (1024 blocks) + transconv_w1 (4096 blocks), period 5
    router_tw1_k<<<5120, 256, 0, stream>>>(x, rw, rb, cnt, tok_e, tok_pos, tok_w,
                                           probs, xb, w1, w1t);
    offsets_scatter_k<<<1, 256, 0, stream>>>(cnt, off, tok_e, tok_pos, tok_w,
                                             rows_tok, roww, g_of);
    // gemm1 (8192 blocks) + transconv_w2 (4096 blocks), period 24 = 16+8
    gemm1_tw2_k<<<12288, 256, 0, stream>>>(xb, w1t, b1, cnt, off, rows_tok, hbuf,
                                           w2, w2t);
    gemm2_k<<<NEXP * 32 * 8 * SPLITK, 256, 0, stream>>>(hbuf, w2t, cnt, off, ybuf);
    combine_aux1_k<<<TOKENS + 16, 256, 0, stream>>>(ybuf, g_of, tok_e, tok_w, b2, out,
                                                    probs, aux_part);
    aux2_k<<<1, 128, 0, stream>>>(aux_part, out + (size_t)TOKENS * DMODEL);
}